// Round 7
// baseline (376.426 us; speedup 1.0000x reference)
//
#include <hip/hip_runtime.h>
#include <hip/hip_bf16.h>
#include <math.h>

#define B_  32
#define L_  4096
#define H_  512
#define V_  32000
#define MBLK 128

typedef __attribute__((ext_vector_type(4))) float f32x4;
typedef __attribute__((ext_vector_type(2))) float f32x2;
typedef __attribute__((ext_vector_type(8))) short short8;
typedef __attribute__((ext_vector_type(4))) unsigned short u16x4;

__device__ __forceinline__ unsigned short bf16_rne(float x){
  union { float f; unsigned int u; } v; v.f = x;
  unsigned int u = v.u;
  return (unsigned short)((u + 0x7FFFu + ((u >> 16) & 1u)) >> 16);
}
// cheap tanh: exact saturation, ~1e-6 abs err
__device__ __forceinline__ float tanh_cheap(float x){
  float e = __expf(x + x);
  return 1.0f - 2.0f * __builtin_amdgcn_rcpf(e + 1.0f);
}
// packed f32x8 -> bf16x8 via v_cvt_pk_bf16_f32
__device__ __forceinline__ short8 cvt8(f32x4 a, f32x4 b){
  union { __hip_bfloat162 h[4]; short8 s; } u;
  u.h[0] = __float22bfloat162_rn(make_float2(a[0], a[1]));
  u.h[1] = __float22bfloat162_rn(make_float2(a[2], a[3]));
  u.h[2] = __float22bfloat162_rn(make_float2(b[0], b[1]));
  u.h[3] = __float22bfloat162_rn(make_float2(b[2], b[3]));
  return u.s;
}

// ---------------- W2 -> bf16 (512 KB, per call) ----------------
__global__ __launch_bounds__(256) void k_convert_w2(
    const float* __restrict__ w2, unsigned short* __restrict__ hi){
  int i = (blockIdx.x * 256 + threadIdx.x) * 4;
  f32x4 v = *(const f32x4*)(w2 + i);
  u16x4 h;
  #pragma unroll
  for (int e = 0; e < 4; ++e) h[e] = bf16_rne(v[e]);
  *(u16x4*)(hi + i) = h;
}

// ---------------- gates ----------------
__global__ __launch_bounds__(256) void k_gates(
    const float* __restrict__ x, const float* __restrict__ h0,
    const float* __restrict__ Wih, const float* __restrict__ Whh,
    const float* __restrict__ bih, const float* __restrict__ bhh,
    float* __restrict__ gates){
  __shared__ float sx[H_], sh[H_];
  int b = blockIdx.y, t = threadIdx.x;
  sx[t] = x[b*H_ + t]; sx[t+256] = x[b*H_ + t + 256];
  sh[t] = h0[b*H_ + t]; sh[t+256] = h0[b*H_ + t + 256];
  __syncthreads();
  int j = blockIdx.x * 256 + t;
  const float* wi = Wih + j*H_;
  const float* wh = Whh + j*H_;
  float acc = bih[j] + bhh[j];
  #pragma unroll 4
  for (int k = 0; k < H_; k += 4) {
    f32x4 a = *(const f32x4*)(wi + k);
    f32x4 c = *(const f32x4*)(wh + k);
    acc += a[0]*sx[k] + a[1]*sx[k+1] + a[2]*sx[k+2] + a[3]*sx[k+3];
    acc += c[0]*sh[k] + c[1]*sh[k+1] + c[2]*sh[k+2] + c[3]*sh[k+3];
  }
  gates[b*2048 + j] = acc;
}

// ---------------- LSTM cell (exact tanh; mirrors h into f32 cc + bf16 ccb) -
__global__ __launch_bounds__(256) void k_lstm(
    const float* __restrict__ gates, const float* __restrict__ c0,
    float* __restrict__ out_h, float* __restrict__ out_c, float* __restrict__ cc,
    unsigned short* __restrict__ ccb){
  int idx = blockIdx.x * 256 + threadIdx.x;   // 16384
  int b = idx >> 9, hh = idx & 511;
  const float* g = gates + b*2048;
  float gi = g[hh], gf = g[512+hh], gg = g[1024+hh], go = g[1536+hh];
  float si = 1.f/(1.f+expf(-gi));
  float sf = 1.f/(1.f+expf(-gf));
  float so = 1.f/(1.f+expf(-go));
  float c = sf * c0[idx] + si * tanhf(gg);
  float h = so * tanhf(c);
  out_h[idx] = h; out_c[idx] = c;
  cc[b*1024 + hh] = h;
  ccb[b*1024 + hh] = bf16_rne(h);
}

// ---------------- q = h@W1^T + b1 ----------------
__global__ __launch_bounds__(256) void k_q(
    const float* __restrict__ cc, const float* __restrict__ W1,
    const float* __restrict__ b1, float* __restrict__ q){
  __shared__ float shh[H_];
  int b = blockIdx.y, t = threadIdx.x;
  shh[t] = cc[b*1024 + t]; shh[t+256] = cc[b*1024 + t + 256];
  __syncthreads();
  int j = blockIdx.x*256 + t;
  const float* w = W1 + j*H_;
  float acc = b1[j];
  #pragma unroll 4
  for (int k = 0; k < H_; k += 4){
    f32x4 a = *(const f32x4*)(w + k);
    acc += a[0]*shh[k] + a[1]*shh[k+1] + a[2]*shh[k+2] + a[3]*shh[k+3];
  }
  q[b*H_ + j] = acc;
}

// ---------------- scores: m97-style 128x128 tiles, 4-wave blocks -----------
// grid (1024 M-tiles, 4 N-tiles). Block: 256 thr; wave (mh=w>>1, jh=w&1) owns
// a 64m x 64j quadrant: acc = 4mt x 4jj f32x4 = 64 AGPR -> 2 indep blocks/CU.
// A = doc bf16 in LDS [row][chunk^(row&7)][8], dbuf. B = W2 bf16 from L2.
// Epilogue: tanh + u1-dot partial over this block's 128 j's -> scorep[nt][l].
__global__ __launch_bounds__(256, 2) void k_scores(
    const float* __restrict__ doc, const unsigned short* __restrict__ w2hi,
    const float* __restrict__ qv,
    const float* __restrict__ w2b, const float* __restrict__ u1,
    float* __restrict__ scorep){
  __shared__ short Ah[2][MBLK][8][8];        // 32 KB
  __shared__ float2 s_qu[128];               // 1 KB
  __shared__ float s_part[2][MBLK];          // 1 KB
  int t = threadIdx.x;
  int row0 = blockIdx.x * MBLK;
  int j0 = blockIdx.y * 128;
  int b = row0 >> 12;
  if (t < 128){
    int j = j0 + t;
    s_qu[t] = make_float2(qv[b*512 + j] + w2b[j], u1[j]);
  }

  // staging: 4 thr/row-pass, 2 row-passes (rows r and r+64), 16 floats each
  int r1 = t >> 2;            // 0..63
  int sg = t & 3;             // 16-float group
  const float* dbase1 = doc + (((long)(row0 + r1)) << 9) + sg*16;
  const float* dbase2 = dbase1 + (64 << 9);
  int wc0 = (2*sg)     ^ (r1 & 7);
  int wc1 = (2*sg + 1) ^ (r1 & 7);
  int r2 = r1 + 64;
  int vc0 = (2*sg)     ^ (r2 & 7);
  int vc1 = (2*sg + 1) ^ (r2 & 7);

  int wave = t >> 6, lane = t & 63;
  int mh = wave >> 1, jh = wave & 1;
  int lrow = lane & 15, lk = lane >> 4;
  const unsigned short* pbh = w2hi + (j0 + jh*64 + lrow)*512 + lk*8;

  f32x4 acc[4][4];  // [mt][jj]
  #pragma unroll
  for (int mt = 0; mt < 4; ++mt)
    #pragma unroll
    for (int jj = 0; jj < 4; ++jj)
      acc[mt][jj] = (f32x4){0.f, 0.f, 0.f, 0.f};

  { // stage step 0
    f32x4 v0 = *(const f32x4*)(dbase1);
    f32x4 v1 = *(const f32x4*)(dbase1 + 4);
    f32x4 v2 = *(const f32x4*)(dbase1 + 8);
    f32x4 v3 = *(const f32x4*)(dbase1 + 12);
    f32x4 u0 = *(const f32x4*)(dbase2);
    f32x4 u1v = *(const f32x4*)(dbase2 + 4);
    f32x4 u2 = *(const f32x4*)(dbase2 + 8);
    f32x4 u3 = *(const f32x4*)(dbase2 + 12);
    *(short8*)&Ah[0][r1][wc0][0] = cvt8(v0, v1);
    *(short8*)&Ah[0][r1][wc1][0] = cvt8(v2, v3);
    *(short8*)&Ah[0][r2][vc0][0] = cvt8(u0, u1v);
    *(short8*)&Ah[0][r2][vc1][0] = cvt8(u2, u3);
  }
  __syncthreads();

  int buf = 0;
  for (int s = 0; s < 8; ++s){
    // B fragments for the whole K-step
    short8 bh[8];
    {
      int ko = s*64;
      #pragma unroll
      for (int jj = 0; jj < 4; ++jj){
        bh[jj]   = *(const short8*)(pbh + jj*8192 + ko);
        bh[4+jj] = *(const short8*)(pbh + jj*8192 + ko + 32);
      }
    }
    // doc prefetch for next step
    f32x4 pv[8];
    if (s < 7){
      const float* p1 = dbase1 + (s+1)*64;
      const float* p2 = dbase2 + (s+1)*64;
      #pragma unroll
      for (int i = 0; i < 4; ++i) pv[i] = *(const f32x4*)(p1 + i*4);
      #pragma unroll
      for (int i = 0; i < 4; ++i) pv[4+i] = *(const f32x4*)(p2 + i*4);
    }
    #pragma unroll
    for (int ktl = 0; ktl < 2; ++ktl){
      short8 a[4];
      #pragma unroll
      for (int mt = 0; mt < 4; ++mt){
        int row = mh*64 + mt*16 + lrow;
        a[mt] = *(const short8*)&Ah[buf][row][(ktl*4 + lk) ^ (row & 7)][0];
      }
      #pragma unroll
      for (int jj = 0; jj < 4; ++jj)
        #pragma unroll
        for (int mt = 0; mt < 4; ++mt)
          acc[mt][jj] = __builtin_amdgcn_mfma_f32_16x16x32_bf16(bh[ktl*4 + jj], a[mt], acc[mt][jj], 0, 0, 0);
    }
    if (s < 7){
      *(short8*)&Ah[buf^1][r1][wc0][0] = cvt8(pv[0], pv[1]);
      *(short8*)&Ah[buf^1][r1][wc1][0] = cvt8(pv[2], pv[3]);
      *(short8*)&Ah[buf^1][r2][vc0][0] = cvt8(pv[4], pv[5]);
      *(short8*)&Ah[buf^1][r2][vc1][0] = cvt8(pv[6], pv[7]);
    }
    __syncthreads();
    buf ^= 1;
  }

  // epilogue: tanh + u1-dot over this wave's 64 j's, per m-row
  #pragma unroll
  for (int mt = 0; mt < 4; ++mt){
    float p = 0.f;
    #pragma unroll
    for (int jj = 0; jj < 4; ++jj){
      #pragma unroll
      for (int r = 0; r < 4; ++r){
        int jl = jh*64 + jj*16 + lk*4 + r;   // 0..127 within block's j-slice
        float2 qu = s_qu[jl];
        p += tanh_cheap(acc[mt][jj][r] + qu.x) * qu.y;
      }
    }
    p += __shfl_xor(p, 16);
    p += __shfl_xor(p, 32);
    if (lane < 16) s_part[jh][mh*64 + mt*16 + lrow] = p;
  }
  __syncthreads();
  if (t < MBLK){
    scorep[(long)blockIdx.y * 131072 + row0 + t] = s_part[0][t] + s_part[1][t];
  }
}

// ---------------- softmax over L per row b (4 partials + mask -> attn) ----
__global__ __launch_bounds__(256) void k_softmax(
    const float* __restrict__ sp, const int* __restrict__ mask,
    float* __restrict__ attn){
  __shared__ float red[256];
  int b = blockIdx.x, t = threadIdx.x;
  float v[16]; float m = -INFINITY;
  #pragma unroll
  for (int i = 0; i < 16; ++i){
    int gl = b*4096 + i*256 + t;
    float s = sp[gl] + sp[131072 + gl] + sp[262144 + gl] + sp[393216 + gl];
    v[i] = mask[gl] ? s : -INFINITY;
    m = fmaxf(m, v[i]);
  }
  red[t] = m; __syncthreads();
  for (int s = 128; s > 0; s >>= 1){ if (t < s) red[t] = fmaxf(red[t], red[t+s]); __syncthreads(); }
  m = red[0]; __syncthreads();
  float sum = 0.f;
  #pragma unroll
  for (int i = 0; i < 16; ++i){ v[i] = expf(v[i] - m); sum += v[i]; }
  red[t] = sum; __syncthreads();
  for (int s = 128; s > 0; s >>= 1){ if (t < s) red[t] += red[t+s]; __syncthreads(); }
  float inv = 1.f / red[0];
  #pragma unroll
  for (int i = 0; i < 16; ++i) attn[b*4096 + i*256 + t] = v[i] * inv;
}

// ---------------- context partials ----------------
#define CCH 64
__global__ __launch_bounds__(256) void k_ctx(
    const float* __restrict__ attn, const float* __restrict__ doc,
    float* __restrict__ ctxp){
  __shared__ float sa[CCH];
  int b = blockIdx.y, ch = blockIdx.x, t = threadIdx.x;
  int l0 = ch * CCH;
  if (t < CCH) sa[t] = attn[b*4096 + l0 + t];
  __syncthreads();
  const float* dp = doc + (((long)b*4096 + l0) << 9) + t*2;
  float ax = 0.f, ay = 0.f;
  #pragma unroll 4
  for (int l = 0; l < CCH; ++l){
    f32x2 d = *(const f32x2*)dp;
    float a = sa[l];
    ax += a * d[0]; ay += a * d[1];
    dp += 512;
  }
  int o = (b*64 + ch)*512 + t*2;
  ctxp[o] = ax; ctxp[o+1] = ay;
}

__global__ __launch_bounds__(256) void k_ctx_reduce(
    const float* __restrict__ ctxp, float* __restrict__ cc,
    unsigned short* __restrict__ ccb){
  int idx = blockIdx.x*256 + threadIdx.x;  // 16384
  int b = idx >> 9, hh = idx & 511;
  float s = 0.f;
  #pragma unroll 8
  for (int ch = 0; ch < 64; ++ch) s += ctxp[(b*64 + ch)*512 + hh];
  cc[b*1024 + 512 + hh] = s;
  ccb[b*1024 + 512 + hh] = bf16_rne(s);
}

// ---------------- output = cc @ Wout^T + bout, bf16 MFMA ----------------
__global__ __launch_bounds__(256) void k_out(
    const unsigned short* __restrict__ ccb, const float* __restrict__ Wout,
    const float* __restrict__ bout, float* __restrict__ out){
  __shared__ short Ccb[32][128][8];      // 64 KB
  __shared__ float s_out[32][65];        // 8.3 KB
  int t = threadIdx.x, wave = t >> 6, lane = t & 63;
  int v0 = blockIdx.x * 64;
  #pragma unroll
  for (int i = 0; i < 16; ++i){
    int c16 = i*256 + t;               // 16B-chunk index over 4096
    int bb = c16 >> 7, ch = c16 & 127;
    int chsw = (ch & ~7) | ((ch & 7) ^ (bb & 7));
    *(short8*)&Ccb[bb][chsw][0] = *(const short8*)(ccb + c16*8);
  }
  __syncthreads();

  int lrow = lane & 15, lk = lane >> 4;
  int vrow = v0 + wave*16 + lrow;
  const float* wptr = Wout + (long)vrow*1024 + lk*8;
  f32x4 acc[2];
  acc[0] = (f32x4){0.f,0.f,0.f,0.f};
  acc[1] = (f32x4){0.f,0.f,0.f,0.f};
  int sw = lrow & 7;
  f32x4 w0 = *(const f32x4*)(wptr);
  f32x4 w1 = *(const f32x4*)(wptr + 4);
  #pragma unroll 4
  for (int ks = 0; ks < 32; ++ks){
    f32x4 nw0, nw1;
    if (ks < 31){
      nw0 = *(const f32x4*)(wptr + (ks+1)*32);
      nw1 = *(const f32x4*)(wptr + (ks+1)*32 + 4);
    }
    short8 bfrag = cvt8(w0, w1);
    int ch = ks*4 + lk;
    int chsw = (ch & ~7) | ((ch & 7) ^ sw);
    short8 a0 = *(const short8*)&Ccb[lrow][chsw][0];
    short8 a1 = *(const short8*)&Ccb[16 + lrow][chsw][0];
    acc[0] = __builtin_amdgcn_mfma_f32_16x16x32_bf16(bfrag, a0, acc[0], 0, 0, 0);
    acc[1] = __builtin_amdgcn_mfma_f32_16x16x32_bf16(bfrag, a1, acc[1], 0, 0, 0);
    w0 = nw0; w1 = nw1;
  }
  #pragma unroll
  for (int mt = 0; mt < 2; ++mt)
    #pragma unroll
    for (int r = 0; r < 4; ++r)
      s_out[mt*16 + lrow][wave*16 + lk*4 + r] = acc[mt][r];
  __syncthreads();
  int vcol = t & 63, bq = t >> 6;
  float bo = bout[v0 + vcol];
  #pragma unroll
  for (int bb = 0; bb < 8; ++bb){
    int brow = bb*4 + bq;
    out[(long)brow*V_ + v0 + vcol] = s_out[brow][vcol] + bo;
  }
}

extern "C" void kernel_launch(void* const* d_in, const int* in_sizes, int n_in,
                              void* d_out, int out_size, void* d_ws, size_t ws_size,
                              hipStream_t stream){
  const float* x    = (const float*)d_in[0];
  const float* h0   = (const float*)d_in[1];
  const float* c0   = (const float*)d_in[2];
  const float* doc  = (const float*)d_in[3];
  const int*   mask = (const int*)d_in[4];
  const float* Wih  = (const float*)d_in[5];
  const float* Whh  = (const float*)d_in[6];
  const float* bih  = (const float*)d_in[7];
  const float* bhh  = (const float*)d_in[8];
  const float* W1   = (const float*)d_in[9];
  const float* b1   = (const float*)d_in[10];
  const float* W2   = (const float*)d_in[11];
  const float* b2   = (const float*)d_in[12];
  const float* u1   = (const float*)d_in[13];
  const float* Wo   = (const float*)d_in[14];
  const float* bo   = (const float*)d_in[15];
  float* out  = (float*)d_out;
  float* outh = out + B_*V_;
  float* outc = outh + B_*H_;

  float* ws    = (float*)d_ws;
  float* gates = ws;                  // 65536 f32
  float* q     = gates + 65536;       // 16384
  float* cc    = q + 16384;           // 32768
  float* attn  = cc + 32768;          // 131072
  float* scorep= attn + 131072;       // 4*131072 = 524288
  float* ctxp  = scorep + 524288;     // 1048576
  unsigned short* w2hi = (unsigned short*)(ctxp + 1048576); // 262144 u16
  unsigned short* ccb  = w2hi + 262144;                      // 32768 u16

  hipLaunchKernelGGL(k_convert_w2, dim3(256), dim3(256), 0, stream, W2, w2hi);
  hipLaunchKernelGGL(k_gates, dim3(8, 32), dim3(256), 0, stream, x, h0, Wih, Whh, bih, bhh, gates);
  hipLaunchKernelGGL(k_lstm, dim3(64), dim3(256), 0, stream, gates, c0, outh, outc, cc, ccb);
  hipLaunchKernelGGL(k_q, dim3(2, 32), dim3(256), 0, stream, cc, W1, b1, q);
  hipLaunchKernelGGL(k_scores, dim3(1024, 4), dim3(256), 0, stream, doc, w2hi, q, b2, u1, scorep);
  hipLaunchKernelGGL(k_softmax, dim3(32), dim3(256), 0, stream, scorep, mask, attn);
  hipLaunchKernelGGL(k_ctx, dim3(64, 32), dim3(256), 0, stream, attn, doc, ctxp);
  hipLaunchKernelGGL(k_ctx_reduce, dim3(64), dim3(256), 0, stream, ctxp, cc, ccb);
  hipLaunchKernelGGL(k_out, dim3(500), dim3(256), 0, stream, ccb, Wo, bo, out);
}

// Round 8
// 301.861 us; speedup vs baseline: 1.2470x; 1.2470x over previous
//
#include <hip/hip_runtime.h>
#include <hip/hip_bf16.h>
#include <math.h>

#define B_  32
#define L_  4096
#define H_  512
#define V_  32000
#define MBLK 64

typedef __attribute__((ext_vector_type(4))) float f32x4;
typedef __attribute__((ext_vector_type(2))) float f32x2;
typedef __attribute__((ext_vector_type(8))) short short8;
typedef __attribute__((ext_vector_type(4))) unsigned short u16x4;

__device__ __forceinline__ unsigned short bf16_rne(float x){
  union { float f; unsigned int u; } v; v.f = x;
  unsigned int u = v.u;
  return (unsigned short)((u + 0x7FFFu + ((u >> 16) & 1u)) >> 16);
}
// cheap tanh: exact saturation, ~1e-6 abs err
__device__ __forceinline__ float tanh_cheap(float x){
  float e = __expf(x + x);
  return 1.0f - 2.0f * __builtin_amdgcn_rcpf(e + 1.0f);
}
// packed f32x8 -> bf16x8 via v_cvt_pk_bf16_f32
__device__ __forceinline__ short8 cvt8(f32x4 a, f32x4 b){
  union { __hip_bfloat162 h[4]; short8 s; } u;
  u.h[0] = __float22bfloat162_rn(make_float2(a[0], a[1]));
  u.h[1] = __float22bfloat162_rn(make_float2(a[2], a[3]));
  u.h[2] = __float22bfloat162_rn(make_float2(b[0], b[1]));
  u.h[3] = __float22bfloat162_rn(make_float2(b[2], b[3]));
  return u.s;
}

// ---------------- W2 -> bf16 (512 KB, per call) ----------------
__global__ __launch_bounds__(256) void k_convert_w2(
    const float* __restrict__ w2, unsigned short* __restrict__ hi){
  int i = (blockIdx.x * 256 + threadIdx.x) * 4;
  f32x4 v = *(const f32x4*)(w2 + i);
  u16x4 h;
  #pragma unroll
  for (int e = 0; e < 4; ++e) h[e] = bf16_rne(v[e]);
  *(u16x4*)(hi + i) = h;
}

// ---------------- gates ----------------
__global__ __launch_bounds__(256) void k_gates(
    const float* __restrict__ x, const float* __restrict__ h0,
    const float* __restrict__ Wih, const float* __restrict__ Whh,
    const float* __restrict__ bih, const float* __restrict__ bhh,
    float* __restrict__ gates){
  __shared__ float sx[H_], sh[H_];
  int b = blockIdx.y, t = threadIdx.x;
  sx[t] = x[b*H_ + t]; sx[t+256] = x[b*H_ + t + 256];
  sh[t] = h0[b*H_ + t]; sh[t+256] = h0[b*H_ + t + 256];
  __syncthreads();
  int j = blockIdx.x * 256 + t;
  const float* wi = Wih + j*H_;
  const float* wh = Whh + j*H_;
  float acc = bih[j] + bhh[j];
  #pragma unroll 4
  for (int k = 0; k < H_; k += 4) {
    f32x4 a = *(const f32x4*)(wi + k);
    f32x4 c = *(const f32x4*)(wh + k);
    acc += a[0]*sx[k] + a[1]*sx[k+1] + a[2]*sx[k+2] + a[3]*sx[k+3];
    acc += c[0]*sh[k] + c[1]*sh[k+1] + c[2]*sh[k+2] + c[3]*sh[k+3];
  }
  gates[b*2048 + j] = acc;
}

// ---------------- LSTM cell (exact tanh; mirrors h into f32 cc + bf16 ccb) -
__global__ __launch_bounds__(256) void k_lstm(
    const float* __restrict__ gates, const float* __restrict__ c0,
    float* __restrict__ out_h, float* __restrict__ out_c, float* __restrict__ cc,
    unsigned short* __restrict__ ccb){
  int idx = blockIdx.x * 256 + threadIdx.x;   // 16384
  int b = idx >> 9, hh = idx & 511;
  const float* g = gates + b*2048;
  float gi = g[hh], gf = g[512+hh], gg = g[1024+hh], go = g[1536+hh];
  float si = 1.f/(1.f+expf(-gi));
  float sf = 1.f/(1.f+expf(-gf));
  float so = 1.f/(1.f+expf(-go));
  float c = sf * c0[idx] + si * tanhf(gg);
  float h = so * tanhf(c);
  out_h[idx] = h; out_c[idx] = c;
  cc[b*1024 + hh] = h;
  ccb[b*1024 + hh] = bf16_rne(h);
}

// ---------------- q = h@W1^T + b1 ----------------
__global__ __launch_bounds__(256) void k_q(
    const float* __restrict__ cc, const float* __restrict__ W1,
    const float* __restrict__ b1, float* __restrict__ q){
  __shared__ float shh[H_];
  int b = blockIdx.y, t = threadIdx.x;
  shh[t] = cc[b*1024 + t]; shh[t+256] = cc[b*1024 + t + 256];
  __syncthreads();
  int j = blockIdx.x*256 + t;
  const float* w = W1 + j*H_;
  float acc = b1[j];
  #pragma unroll 4
  for (int k = 0; k < H_; k += 4){
    f32x4 a = *(const f32x4*)(w + k);
    acc += a[0]*shh[k] + a[1]*shh[k+1] + a[2]*shh[k+2] + a[3]*shh[k+3];
  }
  q[b*H_ + j] = acc;
}

// ---------------- scores: 64-row tile, full N=512, 2 blocks/CU -------------
// 8 waves, launch_bounds(512,4) -> <=128 regs -> 4 waves/SIMD = 2 independent
// 8-wave blocks per CU (barrier drains overlap across blocks). Wave owns
// 64m x 64j: acc = 4mt x 4jj f32x4 = 64 AGPR. B loaded per-ktl (16 VGPR).
// A = doc bf16 in LDS [row][chunk^(row&7)][8], dbuf, conflict-free.
__global__ __launch_bounds__(512, 4) void k_scores(
    const float* __restrict__ doc, const unsigned short* __restrict__ w2hi,
    const float* __restrict__ qv,
    const float* __restrict__ w2b, const float* __restrict__ u1,
    const int* __restrict__ mask, float* __restrict__ scores){
  __shared__ short Ah[2][MBLK][8][8];        // 16 KB
  __shared__ float2 s_qu[512];               // 4 KB
  __shared__ float s_part[8][MBLK];          // 2 KB
  int t = threadIdx.x;
  int row0 = blockIdx.x * MBLK;
  int b = row0 >> 12;
  s_qu[t] = make_float2(qv[b*512 + t] + w2b[t], u1[t]);

  // staging: thread = (row sr = t>>3, 8-float chunk sg = t&7)
  int sr = t >> 3;
  int sg = t & 7;
  const float* dbase = doc + (((long)(row0 + sr)) << 9) + sg*8;
  int wc = sg ^ (sr & 7);

  int wave = t >> 6, lane = t & 63;
  int lrow = lane & 15, lk = lane >> 4;
  int j0 = wave * 64;
  const unsigned short* pbh = w2hi + (j0 + lrow)*512 + lk*8;

  f32x4 acc[4][4];  // [mt][jj]
  #pragma unroll
  for (int mt = 0; mt < 4; ++mt)
    #pragma unroll
    for (int jj = 0; jj < 4; ++jj)
      acc[mt][jj] = (f32x4){0.f, 0.f, 0.f, 0.f};

  { // stage step 0
    f32x4 v0 = *(const f32x4*)(dbase);
    f32x4 v1 = *(const f32x4*)(dbase + 4);
    *(short8*)&Ah[0][sr][wc][0] = cvt8(v0, v1);
  }
  __syncthreads();

  int buf = 0;
  for (int s = 0; s < 8; ++s){
    // doc prefetch for next step (issue early, consume after MFMA)
    f32x4 pf0, pf1;
    if (s < 7){
      const float* p = dbase + (s+1)*64;
      pf0 = *(const f32x4*)(p);
      pf1 = *(const f32x4*)(p + 4);
    }
    #pragma unroll
    for (int ktl = 0; ktl < 2; ++ktl){
      short8 bh[4];
      int ko = s*64 + ktl*32;
      #pragma unroll
      for (int jj = 0; jj < 4; ++jj)
        bh[jj] = *(const short8*)(pbh + jj*8192 + ko);
      short8 a[4];
      #pragma unroll
      for (int mt = 0; mt < 4; ++mt){
        int row = mt*16 + lrow;
        a[mt] = *(const short8*)&Ah[buf][row][(ktl*4 + lk) ^ (row & 7)][0];
      }
      #pragma unroll
      for (int jj = 0; jj < 4; ++jj)
        #pragma unroll
        for (int mt = 0; mt < 4; ++mt)
          acc[mt][jj] = __builtin_amdgcn_mfma_f32_16x16x32_bf16(bh[jj], a[mt], acc[mt][jj], 0, 0, 0);
    }
    if (s < 7)
      *(short8*)&Ah[buf^1][sr][wc][0] = cvt8(pf0, pf1);
    __syncthreads();
    buf ^= 1;
  }

  // epilogue: tanh + u1-dot over wave's 64 j's, per m-row
  #pragma unroll
  for (int mt = 0; mt < 4; ++mt){
    float p = 0.f;
    #pragma unroll
    for (int jj = 0; jj < 4; ++jj){
      #pragma unroll
      for (int r = 0; r < 4; ++r){
        int j = j0 + jj*16 + lk*4 + r;
        float2 qu = s_qu[j];
        p += tanh_cheap(acc[mt][jj][r] + qu.x) * qu.y;
      }
    }
    p += __shfl_xor(p, 16);
    p += __shfl_xor(p, 32);
    if (lane < 16) s_part[wave][mt*16 + lrow] = p;
  }
  __syncthreads();
  if (t < MBLK){
    float ssum = 0.f;
    #pragma unroll
    for (int w = 0; w < 8; ++w) ssum += s_part[w][t];
    int gl = row0 + t;
    scores[gl] = mask[gl] ? ssum : -INFINITY;
  }
}

// ---------------- softmax over L per row b (in place) ----------------
__global__ __launch_bounds__(256) void k_softmax(float* __restrict__ sc){
  __shared__ float red[256];
  int b = blockIdx.x, t = threadIdx.x;
  float v[16]; float m = -INFINITY;
  #pragma unroll
  for (int i = 0; i < 16; ++i){ v[i] = sc[b*4096 + i*256 + t]; m = fmaxf(m, v[i]); }
  red[t] = m; __syncthreads();
  for (int s = 128; s > 0; s >>= 1){ if (t < s) red[t] = fmaxf(red[t], red[t+s]); __syncthreads(); }
  m = red[0]; __syncthreads();
  float sum = 0.f;
  #pragma unroll
  for (int i = 0; i < 16; ++i){ v[i] = expf(v[i] - m); sum += v[i]; }
  red[t] = sum; __syncthreads();
  for (int s = 128; s > 0; s >>= 1){ if (t < s) red[t] += red[t+s]; __syncthreads(); }
  float inv = 1.f / red[0];
  #pragma unroll
  for (int i = 0; i < 16; ++i) sc[b*4096 + i*256 + t] = v[i] * inv;
}

// ---------------- context partials ----------------
#define CCH 64
__global__ __launch_bounds__(256) void k_ctx(
    const float* __restrict__ attn, const float* __restrict__ doc,
    float* __restrict__ ctxp){
  __shared__ float sa[CCH];
  int b = blockIdx.y, ch = blockIdx.x, t = threadIdx.x;
  int l0 = ch * CCH;
  if (t < CCH) sa[t] = attn[b*4096 + l0 + t];
  __syncthreads();
  const float* dp = doc + (((long)b*4096 + l0) << 9) + t*2;
  float ax = 0.f, ay = 0.f;
  #pragma unroll 4
  for (int l = 0; l < CCH; ++l){
    f32x2 d = *(const f32x2*)dp;
    float a = sa[l];
    ax += a * d[0]; ay += a * d[1];
    dp += 512;
  }
  int o = (b*64 + ch)*512 + t*2;
  ctxp[o] = ax; ctxp[o+1] = ay;
}

__global__ __launch_bounds__(256) void k_ctx_reduce(
    const float* __restrict__ ctxp, float* __restrict__ cc,
    unsigned short* __restrict__ ccb){
  int idx = blockIdx.x*256 + threadIdx.x;  // 16384
  int b = idx >> 9, hh = idx & 511;
  float s = 0.f;
  #pragma unroll 8
  for (int ch = 0; ch < 64; ++ch) s += ctxp[(b*64 + ch)*512 + hh];
  cc[b*1024 + 512 + hh] = s;
  ccb[b*1024 + 512 + hh] = bf16_rne(s);
}

// ---------------- output = cc @ Wout^T + bout, bf16 MFMA ----------------
__global__ __launch_bounds__(256) void k_out(
    const unsigned short* __restrict__ ccb, const float* __restrict__ Wout,
    const float* __restrict__ bout, float* __restrict__ out){
  __shared__ short Ccb[32][128][8];      // 64 KB
  __shared__ float s_out[32][65];        // 8.3 KB
  int t = threadIdx.x, wave = t >> 6, lane = t & 63;
  int v0 = blockIdx.x * 64;
  #pragma unroll
  for (int i = 0; i < 16; ++i){
    int c16 = i*256 + t;               // 16B-chunk index over 4096
    int bb = c16 >> 7, ch = c16 & 127;
    int chsw = (ch & ~7) | ((ch & 7) ^ (bb & 7));
    *(short8*)&Ccb[bb][chsw][0] = *(const short8*)(ccb + c16*8);
  }
  __syncthreads();

  int lrow = lane & 15, lk = lane >> 4;
  int vrow = v0 + wave*16 + lrow;
  const float* wptr = Wout + (long)vrow*1024 + lk*8;
  f32x4 acc[2];
  acc[0] = (f32x4){0.f,0.f,0.f,0.f};
  acc[1] = (f32x4){0.f,0.f,0.f,0.f};
  int sw = lrow & 7;
  f32x4 w0 = *(const f32x4*)(wptr);
  f32x4 w1 = *(const f32x4*)(wptr + 4);
  #pragma unroll 4
  for (int ks = 0; ks < 32; ++ks){
    f32x4 nw0, nw1;
    if (ks < 31){
      nw0 = *(const f32x4*)(wptr + (ks+1)*32);
      nw1 = *(const f32x4*)(wptr + (ks+1)*32 + 4);
    }
    short8 bfrag = cvt8(w0, w1);
    int ch = ks*4 + lk;
    int chsw = (ch & ~7) | ((ch & 7) ^ sw);
    short8 a0 = *(const short8*)&Ccb[lrow][chsw][0];
    short8 a1 = *(const short8*)&Ccb[16 + lrow][chsw][0];
    acc[0] = __builtin_amdgcn_mfma_f32_16x16x32_bf16(bfrag, a0, acc[0], 0, 0, 0);
    acc[1] = __builtin_amdgcn_mfma_f32_16x16x32_bf16(bfrag, a1, acc[1], 0, 0, 0);
    w0 = nw0; w1 = nw1;
  }
  #pragma unroll
  for (int mt = 0; mt < 2; ++mt)
    #pragma unroll
    for (int r = 0; r < 4; ++r)
      s_out[mt*16 + lrow][wave*16 + lk*4 + r] = acc[mt][r];
  __syncthreads();
  int vcol = t & 63, bq = t >> 6;
  float bo = bout[v0 + vcol];
  #pragma unroll
  for (int bb = 0; bb < 8; ++bb){
    int brow = bb*4 + bq;
    out[(long)brow*V_ + v0 + vcol] = s_out[brow][vcol] + bo;
  }
}

extern "C" void kernel_launch(void* const* d_in, const int* in_sizes, int n_in,
                              void* d_out, int out_size, void* d_ws, size_t ws_size,
                              hipStream_t stream){
  const float* x    = (const float*)d_in[0];
  const float* h0   = (const float*)d_in[1];
  const float* c0   = (const float*)d_in[2];
  const float* doc  = (const float*)d_in[3];
  const int*   mask = (const int*)d_in[4];
  const float* Wih  = (const float*)d_in[5];
  const float* Whh  = (const float*)d_in[6];
  const float* bih  = (const float*)d_in[7];
  const float* bhh  = (const float*)d_in[8];
  const float* W1   = (const float*)d_in[9];
  const float* b1   = (const float*)d_in[10];
  const float* W2   = (const float*)d_in[11];
  const float* b2   = (const float*)d_in[12];
  const float* u1   = (const float*)d_in[13];
  const float* Wo   = (const float*)d_in[14];
  const float* bo   = (const float*)d_in[15];
  float* out  = (float*)d_out;
  float* outh = out + B_*V_;
  float* outc = outh + B_*H_;

  float* ws    = (float*)d_ws;
  float* gates = ws;                  // 65536 f32
  float* q     = gates + 65536;       // 16384
  float* cc    = q + 16384;           // 32768
  float* attn  = cc + 32768;          // 131072
  float* ctxp  = attn + 131072;       // 1048576
  unsigned short* w2hi = (unsigned short*)(ctxp + 1048576); // 262144 u16
  unsigned short* ccb  = w2hi + 262144;                      // 32768 u16

  hipLaunchKernelGGL(k_convert_w2, dim3(256), dim3(256), 0, stream, W2, w2hi);
  hipLaunchKernelGGL(k_gates, dim3(8, 32), dim3(256), 0, stream, x, h0, Wih, Whh, bih, bhh, gates);
  hipLaunchKernelGGL(k_lstm, dim3(64), dim3(256), 0, stream, gates, c0, outh, outc, cc, ccb);
  hipLaunchKernelGGL(k_q, dim3(2, 32), dim3(256), 0, stream, cc, W1, b1, q);
  hipLaunchKernelGGL(k_scores, dim3(2048), dim3(512), 0, stream, doc, w2hi, q, b2, u1, mask, attn);
  hipLaunchKernelGGL(k_softmax, dim3(32), dim3(256), 0, stream, attn);
  hipLaunchKernelGGL(k_ctx, dim3(64, 32), dim3(256), 0, stream, attn, doc, ctxp);
  hipLaunchKernelGGL(k_ctx_reduce, dim3(64), dim3(256), 0, stream, ctxp, cc, ccb);
  hipLaunchKernelGGL(k_out, dim3(500), dim3(256), 0, stream, ccb, Wo, bo, out);
}